// Round 8
// baseline (31.028 us; speedup 1.0000x reference)
//
#include <hip/hip_runtime.h>
#include <hip/hip_bf16.h>
#include <math.h>

#define NA 4
#define NT 64
#define NC 8
#define NK 1024
#define NR 8
#define NH 64
#define NW 64

typedef __attribute__((ext_vector_type(8))) short bf16x8;
typedef __attribute__((ext_vector_type(4))) float f32x4;

__device__ __forceinline__ float2 cmul2(float2 a, float2 b) {
    return make_float2(fmaf(a.x, b.x, -a.y * b.y), fmaf(a.x, b.y, a.y * b.x));
}

// native trig (v_sin_f32/v_cos_f32 path). |x| <= ~101 rad -> err ~1e-5 rad,
// invisible under bf16 quantization.
__device__ __forceinline__ void fast_sc(float x, float* s, float* c) {
    *s = __sinf(x);
    *c = __cosf(x);
}

// ---------------------------------------------------------------------------
// gemm, LDS-resident A-eighth, zero in-loop staging:
// 512 blocks = (K'-eighth p in 0..7: h in [8p, 8p+8)) x (64 n-groups of 128
// k-points). Phase 1: build A-eighth (64KB bf16, MFMA-frag-linear) from x*mps
// directly into LDS. Phase 2 (after ONE barrier): 32 k-steps of pure
// {ds_read -> B-gen -> MFMA}. Phase 3: write Fre partial [p][32][8192].
// Slot map (R4-verified): uint slot ((ls*2+mt)*64+l)*4+i2 holds (re,im) for
// m = mt*16 + (l&15), hw = p*512 + ls*16 + (l>>4)*4 + i2.
// ---------------------------------------------------------------------------
__global__ __launch_bounds__(512) void gemm_kernel(
    const float* __restrict__ xr, const float* __restrict__ xi,
    const float* __restrict__ mr, const float* __restrict__ mi,
    const float* __restrict__ trj, float* __restrict__ Fre)
{
    __shared__ uint lds[16384];   // 64 KB A-eighth
    int b = blockIdx.x;           // 512
    int tid = threadIdx.x;
    int p  = b & 7;               // K'-eighth
    int ng = b >> 3;              // 64 n-groups
    int wv = tid >> 6, l = tid & 63;
    int lg = l >> 4, ln = l & 15;
    int r = ng >> 3;

    // ---- phase 1: build A-eighth into LDS (8 iters x 512 thr x 16B) ----
    #pragma unroll 2
    for (int it = 0; it < 8; ++it) {
        int sg = it * 512 + tid;          // slot-group (4 uints each), 0..8191
        int sl = sg & 63;
        int mtls = sg >> 6;               // 0..63
        int mt = mtls & 1, ls = mtls >> 1;
        int hw0 = (p << 9) + (ls << 4) + ((sl >> 4) << 2);
        int m = (mt << 4) + (sl & 15);
        int a = m >> 3, c = m & 7;
        union { float4 v; float f[4]; } x4r, x4i, m4r, m4i;
        x4r.v = *(const float4*)(xr + (a << 12) + hw0);
        x4i.v = *(const float4*)(xi + (a << 12) + hw0);
        m4r.v = *(const float4*)(mr + (c << 12) + hw0);
        m4i.v = *(const float4*)(mi + (c << 12) + hw0);
        union { uint u[4]; uint4 v; } pk;
        #pragma unroll
        for (int i = 0; i < 4; ++i) {
            float re = x4r.f[i] * m4r.f[i] - x4i.f[i] * m4i.f[i];
            float im = x4r.f[i] * m4i.f[i] + x4i.f[i] * m4r.f[i];
            __hip_bfloat162 h2 = __float22bfloat162_rn(make_float2(re, im));
            union { __hip_bfloat162 h; uint u; } cu; cu.h = h2;
            pk.u[i] = cu.u;
        }
        *(uint4*)(lds + (sg << 2)) = pk.v;
    }

    // ---- trig prologue (overlaps with other waves' phase-1 tails) ----
    int kloc = ((ng & 7) << 7) + (wv << 4) + ln;   // k within r: 0..1023
    float t0 = trj[(r << 11) + kloc];
    float t1 = trj[(r << 11) + 1024 + kloc];
    float sv, cv;
    float2 ewb[4], st1, st16, st1h, ehc;
    fast_sc(t1 * (float)(32 - (lg << 2)), &sv, &cv); ewb[0] = make_float2(cv, sv);
    fast_sc(-t1, &sv, &cv);         st1  = make_float2(cv, sv);
    fast_sc(-16.0f * t1, &sv, &cv); st16 = make_float2(cv, sv);
    ewb[1] = cmul2(ewb[0], st1);
    ewb[2] = cmul2(ewb[1], st1);
    ewb[3] = cmul2(ewb[2], st1);
    fast_sc(t0 * (float)(32 - (p << 3)), &sv, &cv); ehc = make_float2(cv, sv);  // h0 = 8p
    fast_sc(-t0, &sv, &cv); st1h = make_float2(cv, sv);

    f32x4 acc0 = {0.f, 0.f, 0.f, 0.f}, acc1 = acc0;
    __syncthreads();

    // ---- phase 2: 8 h-rows x 4 w-steps, pure LDS + VALU + MFMA ----
    #pragma unroll 2
    for (int oi = 0; oi < 8; ++oi) {      // h = 8p + oi
        float2 g = ehc;
        #pragma unroll
        for (int j = 0; j < 4; ++j) {     // w = j*16 + lg*4 + i
            int ls = (oi << 2) + j;
            bf16x8 a0 = *(const bf16x8*)(lds + (((ls << 1) + 0) << 8) + (l << 2));
            bf16x8 a1 = *(const bf16x8*)(lds + (((ls << 1) + 1) << 8) + (l << 2));
            union { uint u[4]; bf16x8 v; } bf;
            #pragma unroll
            for (int i = 0; i < 4; ++i) {
                float2 e2 = cmul2(g, ewb[i]);
                __hip_bfloat162 hb = __float22bfloat162_rn(make_float2(e2.x, -e2.y));
                union { __hip_bfloat162 h; uint u; } cu; cu.h = hb;
                bf.u[i] = cu.u;
            }
            acc0 = __builtin_amdgcn_mfma_f32_16x16x32_bf16(a0, bf.v, acc0, 0, 0, 0);
            acc1 = __builtin_amdgcn_mfma_f32_16x16x32_bf16(a1, bf.v, acc1, 0, 0, 0);
            g = cmul2(g, st16);
        }
        ehc = cmul2(ehc, st1h);
    }

    // ---- phase 3: write Fre partial [p][m][rk] (C/D map: col=l&15, row=lg*4+q)
    int rk = (ng << 7) + (wv << 4) + ln;
    #pragma unroll
    for (int q = 0; q < 4; ++q) {
        int m0 = (lg << 2) + q;
        Fre[(p << 18) + (m0 << 13) + rk]        = acc0[q];
        Fre[(p << 18) + ((m0 + 16) << 13) + rk] = acc1[q];
    }
}

// combine: out[t,c,k] = dcf*scale * sum_a phi[a,t] * sum_p Fre[p][a*8+c][r*1024+k]
// float4 over k. 512 blocks x 256 threads = 131072 threads.
__global__ __launch_bounds__(256) void combine_kernel(
    const float* __restrict__ Fre, const float* __restrict__ phi,
    const float* __restrict__ dcf, const int* __restrict__ sidx,
    float* __restrict__ out)
{
    int idx = blockIdx.x * 256 + threadIdx.x;   // T*C*K/4 = 131072
    if (idx >= NT * NC * NK / 4) return;
    int k4 = idx & 255;
    int c  = (idx >> 8) & 7;
    int t  = idx >> 11;
    int r  = sidx[t];
    float4 d4 = *(const float4*)(dcf + (r << 10) + (k4 << 2));
    float4 acc = make_float4(0.f, 0.f, 0.f, 0.f);
    #pragma unroll
    for (int a = 0; a < 4; ++a) {
        int off = (((a << 3) + c) << 13) + (r << 10) + (k4 << 2);
        float4 f = make_float4(0.f, 0.f, 0.f, 0.f);
        #pragma unroll
        for (int pp = 0; pp < 8; ++pp) {
            float4 fp = *(const float4*)(Fre + (pp << 18) + off);
            f.x += fp.x; f.y += fp.y; f.z += fp.z; f.w += fp.w;
        }
        float ph = phi[a * 64 + t];
        acc.x = fmaf(ph, f.x, acc.x);
        acc.y = fmaf(ph, f.y, acc.y);
        acc.z = fmaf(ph, f.z, acc.z);
        acc.w = fmaf(ph, f.w, acc.w);
    }
    float s = 0.03125f;   // 2/sqrt(64*64)
    float4 o = make_float4(acc.x * d4.x * s, acc.y * d4.y * s,
                           acc.z * d4.z * s, acc.w * d4.w * s);
    *(float4*)(out + (idx << 2)) = o;
}

// ---------------- fallback (proven round-3 path, no ws needed) --------------
__global__ __launch_bounds__(256) void ndft_atomic_kernel(
    const float* __restrict__ xr, const float* __restrict__ xi,
    const float* __restrict__ mr, const float* __restrict__ mi,
    const float* __restrict__ trj,
    const float* __restrict__ phi, const float* __restrict__ dcf,
    const int* __restrict__ sidx, float* __restrict__ out)
{
    __shared__ float2 simg[NH * NW];
    int b = blockIdx.x;
    int kq = b & 3, c = (b >> 2) & 7, a = (b >> 5) & 3, r = b >> 7;
    int tid = threadIdx.x;
    for (int i = tid; i < NH * NW; i += 256) {
        float xre = xr[(a << 12) + i], xim = xi[(a << 12) + i];
        float mre = mr[(c << 12) + i], mim = mi[(c << 12) + i];
        simg[i] = make_float2(xre * mre - xim * mim, xre * mim + xim * mre);
    }
    __syncthreads();
    int k = (kq << 8) + tid;
    float t0 = trj[(r << 11) + k];
    float t1 = trj[(r << 11) + 1024 + k];
    float sv, cv;
    sincosf(-t1, &sv, &cv);        float2 ewb = make_float2(cv, sv);
    sincosf(32.0f * t1, &sv, &cv); float2 ews = make_float2(cv, sv);
    sincosf(-t0, &sv, &cv);        float2 ehb = make_float2(cv, sv);
    sincosf(32.0f * t0, &sv, &cv); float2 ehc = make_float2(cv, sv);
    float accx = 0.f;
    for (int h0 = 0; h0 < NH; h0 += 4) {
        float2 s0 = make_float2(0.f, 0.f), s1 = s0, s2 = s0, s3 = s0;
        const float2* i0 = simg + (h0 << 6);
        float2 ewc = ews;
        #pragma unroll 8
        for (int w = 0; w < NW; ++w) {
            float2 v0 = i0[w], v1 = i0[w+64], v2 = i0[w+128], v3 = i0[w+192];
            s0.x = fmaf(v0.x, ewc.x, fmaf(-v0.y, ewc.y, s0.x));
            s0.y = fmaf(v0.x, ewc.y, fmaf( v0.y, ewc.x, s0.y));
            s1.x = fmaf(v1.x, ewc.x, fmaf(-v1.y, ewc.y, s1.x));
            s1.y = fmaf(v1.x, ewc.y, fmaf( v1.y, ewc.x, s1.y));
            s2.x = fmaf(v2.x, ewc.x, fmaf(-v2.y, ewc.y, s2.x));
            s2.y = fmaf(v2.x, ewc.y, fmaf( v2.y, ewc.x, s2.y));
            s3.x = fmaf(v3.x, ewc.x, fmaf(-v3.y, ewc.y, s3.x));
            s3.y = fmaf(v3.x, ewc.y, fmaf( v3.y, ewc.x, s3.y));
            ewc = cmul2(ewc, ewb);
        }
        float2 e0 = ehc, e1 = cmul2(e0, ehb), e2 = cmul2(e1, ehb), e3 = cmul2(e2, ehb);
        ehc = cmul2(e3, ehb);
        accx = fmaf(s0.x, e0.x, fmaf(-s0.y, e0.y, accx));
        accx = fmaf(s1.x, e1.x, fmaf(-s1.y, e1.y, accx));
        accx = fmaf(s2.x, e2.x, fmaf(-s2.y, e2.y, accx));
        accx = fmaf(s3.x, e3.x, fmaf(-s3.y, e3.y, accx));
    }
    float d = dcf[(r << 10) + k] * 0.03125f;
    for (int t = 0; t < NT; ++t) {
        if (sidx[t] == r) atomicAdd(out + (t << 13) + (c << 10) + k, phi[a*64 + t] * d * accx);
    }
}

extern "C" void kernel_launch(void* const* d_in, const int* in_sizes, int n_in,
                              void* d_out, int out_size, void* d_ws, size_t ws_size,
                              hipStream_t stream)
{
    const float* x_re   = (const float*)d_in[0];
    const float* x_im   = (const float*)d_in[1];
    const float* mps_re = (const float*)d_in[2];
    const float* mps_im = (const float*)d_in[3];
    const float* phi    = (const float*)d_in[4];
    const float* dcf    = (const float*)d_in[5];
    const float* trj    = (const float*)d_in[6];
    const int*   sidx   = (const int*)d_in[7];
    float* out = (float*)d_out;

    const size_t F_bytes = 8u * 32 * 8192 * sizeof(float);  // 8 MB partials

    if (ws_size >= F_bytes) {
        float* Fre = (float*)d_ws;
        hipLaunchKernelGGL(gemm_kernel, dim3(512), dim3(512), 0, stream,
                           x_re, x_im, mps_re, mps_im, trj, Fre);
        hipLaunchKernelGGL(combine_kernel, dim3(512), dim3(256), 0, stream,
                           Fre, phi, dcf, sidx, out);
    } else {
        hipMemsetAsync(d_out, 0, (size_t)out_size * sizeof(float), stream);
        hipLaunchKernelGGL(ndft_atomic_kernel, dim3(1024), dim3(256), 0, stream,
                           x_re, x_im, mps_re, mps_im, trj, phi, dcf, sidx, out);
    }
}

// Round 9
// 23.491 us; speedup vs baseline: 1.3209x; 1.3209x over previous
//
#include <hip/hip_runtime.h>
#include <hip/hip_bf16.h>
#include <math.h>

#define NT 64
#define NC 8
#define NK 1024

typedef __attribute__((ext_vector_type(8))) short bf16x8;
typedef __attribute__((ext_vector_type(4))) float f32x4;

__device__ __forceinline__ float2 cmul2(float2 a, float2 b) {
    return make_float2(fmaf(a.x, b.x, -a.y * b.y), fmaf(a.x, b.y, a.y * b.x));
}
// native trig; |x| <= ~101 rad -> err invisible under bf16 quantization
__device__ __forceinline__ void fast_sc(float x, float* s, float* c) {
    *s = __sinf(x); *c = __cosf(x);
}
__device__ __forceinline__ uint pack2(float x, float y) {
    __hip_bfloat162 h2 = __float22bfloat162_rn(make_float2(x, y));
    union { __hip_bfloat162 h; uint u; } cu; cu.h = h2; return cu.u;
}

// ---------------------------------------------------------------------------
// prep: pack A = [img_re, img_im] over k'=2w+ri, rows h, per (a,c) panel, in
// MFMA-frag-linear order: uint4 slot t = (ac*16 + mt*4 + chunk)*64 + l holds
// (re,im) pairs for h = mt*16 + (l&15), w = chunk*16 + (l>>4)*4 + i. 512 KB.
// ---------------------------------------------------------------------------
__global__ __launch_bounds__(256) void prep_kernel(
    const float* __restrict__ xr, const float* __restrict__ xi,
    const float* __restrict__ mr, const float* __restrict__ mi,
    uint4* __restrict__ Ap)
{
    int t = blockIdx.x * 256 + threadIdx.x;   // 32768
    int l = t & 63;
    int chunk = (t >> 6) & 3;
    int mt = (t >> 8) & 3;
    int ac = t >> 10;
    int a = ac >> 3, c = ac & 7;
    int h = (mt << 4) + (l & 15);
    int w0 = (chunk << 4) + ((l >> 4) << 2);
    int off = (h << 6) + w0;
    float4 x4r = *(const float4*)(xr + (a << 12) + off);
    float4 x4i = *(const float4*)(xi + (a << 12) + off);
    float4 m4r = *(const float4*)(mr + (c << 12) + off);
    float4 m4i = *(const float4*)(mi + (c << 12) + off);
    uint4 pk;
    pk.x = pack2(x4r.x * m4r.x - x4i.x * m4i.x, x4r.x * m4i.x + x4i.x * m4r.x);
    pk.y = pack2(x4r.y * m4r.y - x4i.y * m4i.y, x4r.y * m4i.y + x4i.y * m4r.y);
    pk.z = pack2(x4r.z * m4r.z - x4i.z * m4i.z, x4r.z * m4i.z + x4i.z * m4r.z);
    pk.w = pack2(x4r.w * m4r.w - x4i.w * m4i.w, x4r.w * m4i.w + x4i.w * m4r.w);
    Ap[t] = pk;
}

// ---------------------------------------------------------------------------
// gemm2: no LDS, no barriers. 1024 blocks = (256 rk-tiles of 32) x (4 ac-
// groups of 8). Wave owns 2 ac x 32 rk (2 n-subtiles). B (Ew bf16) generated
// once per wave in registers and reused across 128 MFMAs; A-frags streamed
// from L2 via coalesced uint4 loads. Stage-2 (Eh contraction over h) fused
// per (ac, mtile) on fp32 accumulators; cross-lane reduce via shfl_xor.
// ---------------------------------------------------------------------------
__global__ __launch_bounds__(256) void gemm2_kernel(
    const uint4* __restrict__ Ap, const float* __restrict__ trj,
    float* __restrict__ Fre)
{
    int b = blockIdx.x;               // 1024
    int rktile = b >> 2, acg = b & 3;
    int tid = threadIdx.x;
    int wv = tid >> 6, l = tid & 63;
    int lg = l >> 4;
    int rkbase = rktile << 5;
    int r = rkbase >> 10;
    int acb = (acg << 3) + (wv << 1);   // wave's first ac
    int wb = lg << 2;                   // w-base / h-base for this lane group

    int k0 = (rkbase + (l & 15)) & 1023;        // sub0 column's k
    int k1 = (rkbase + 16 + (l & 15)) & 1023;   // sub1 column's k
    float t0a = trj[(r << 11) + k0];
    float t0b = trj[(r << 11) + k1];
    float t1a = trj[(r << 11) + 1024 + k0];
    float t1b = trj[(r << 11) + 1024 + k1];

    // ---- B-frag generation (once per wave): B1=(Ewre,-Ewim), B2=(Ewim,Ewre)
    bf16x8 B1[2][4], B2[2][4];
    #pragma unroll
    for (int s = 0; s < 2; ++s) {
        float t1 = s ? t1b : t1a;
        float sv, cv;
        float2 e, st1, st16;
        fast_sc(t1 * (float)(32 - wb), &sv, &cv); e = make_float2(cv, sv);
        fast_sc(-t1, &sv, &cv);         st1  = make_float2(cv, sv);
        fast_sc(-16.0f * t1, &sv, &cv); st16 = make_float2(cv, sv);
        #pragma unroll
        for (int ch = 0; ch < 4; ++ch) {
            float2 ec = e;
            union { uint u[4]; bf16x8 v; } f1, f2;
            #pragma unroll
            for (int i = 0; i < 4; ++i) {
                f1.u[i] = pack2(ec.x, -ec.y);
                f2.u[i] = pack2(ec.y,  ec.x);
                ec = cmul2(ec, st1);
            }
            B1[s][ch] = f1.v; B2[s][ch] = f2.v;
            e = cmul2(e, st16);
        }
    }

    // ---- Eh bases/steps (per n-subtile: t0 depends on the column)
    float sv, cv;
    float2 ehbA, ehbB, s1A, s1B, s16A, s16B;
    fast_sc(t0a * (float)(32 - wb), &sv, &cv); ehbA = make_float2(cv, sv);
    fast_sc(-t0a, &sv, &cv);         s1A  = make_float2(cv, sv);
    fast_sc(-16.0f * t0a, &sv, &cv); s16A = make_float2(cv, sv);
    fast_sc(t0b * (float)(32 - wb), &sv, &cv); ehbB = make_float2(cv, sv);
    fast_sc(-t0b, &sv, &cv);         s1B  = make_float2(cv, sv);
    fast_sc(-16.0f * t0b, &sv, &cv); s16B = make_float2(cv, sv);

    float ps00 = 0.f, ps01 = 0.f, ps10 = 0.f, ps11 = 0.f;  // [aci][sub]

    #pragma unroll
    for (int mt = 0; mt < 4; ++mt) {
        // Eh for rows h = mt*16 + wb + q
        float2 eA[4], eB[4];
        eA[0] = ehbA; eB[0] = ehbB;
        #pragma unroll
        for (int q = 1; q < 4; ++q) {
            eA[q] = cmul2(eA[q-1], s1A);
            eB[q] = cmul2(eB[q-1], s1B);
        }
        ehbA = cmul2(ehbA, s16A);
        ehbB = cmul2(ehbB, s16B);

        #pragma unroll
        for (int aci = 0; aci < 2; ++aci) {
            int ac = acb + aci;
            const uint4* ap = Ap + (((ac << 4) + (mt << 2)) << 6) + l;
            uint4 a0 = ap[0];
            uint4 a1 = ap[64];
            uint4 a2 = ap[128];
            uint4 a3 = ap[192];
            f32x4 r0 = {0.f,0.f,0.f,0.f}, i0 = r0, r1 = r0, i1 = r0;
            union { uint4 u; bf16x8 v; } av;
            av.u = a0;
            r0 = __builtin_amdgcn_mfma_f32_16x16x32_bf16(av.v, B1[0][0], r0, 0,0,0);
            i0 = __builtin_amdgcn_mfma_f32_16x16x32_bf16(av.v, B2[0][0], i0, 0,0,0);
            r1 = __builtin_amdgcn_mfma_f32_16x16x32_bf16(av.v, B1[1][0], r1, 0,0,0);
            i1 = __builtin_amdgcn_mfma_f32_16x16x32_bf16(av.v, B2[1][0], i1, 0,0,0);
            av.u = a1;
            r0 = __builtin_amdgcn_mfma_f32_16x16x32_bf16(av.v, B1[0][1], r0, 0,0,0);
            i0 = __builtin_amdgcn_mfma_f32_16x16x32_bf16(av.v, B2[0][1], i0, 0,0,0);
            r1 = __builtin_amdgcn_mfma_f32_16x16x32_bf16(av.v, B1[1][1], r1, 0,0,0);
            i1 = __builtin_amdgcn_mfma_f32_16x16x32_bf16(av.v, B2[1][1], i1, 0,0,0);
            av.u = a2;
            r0 = __builtin_amdgcn_mfma_f32_16x16x32_bf16(av.v, B1[0][2], r0, 0,0,0);
            i0 = __builtin_amdgcn_mfma_f32_16x16x32_bf16(av.v, B2[0][2], i0, 0,0,0);
            r1 = __builtin_amdgcn_mfma_f32_16x16x32_bf16(av.v, B1[1][2], r1, 0,0,0);
            i1 = __builtin_amdgcn_mfma_f32_16x16x32_bf16(av.v, B2[1][2], i1, 0,0,0);
            av.u = a3;
            r0 = __builtin_amdgcn_mfma_f32_16x16x32_bf16(av.v, B1[0][3], r0, 0,0,0);
            i0 = __builtin_amdgcn_mfma_f32_16x16x32_bf16(av.v, B2[0][3], i0, 0,0,0);
            r1 = __builtin_amdgcn_mfma_f32_16x16x32_bf16(av.v, B1[1][3], r1, 0,0,0);
            i1 = __builtin_amdgcn_mfma_f32_16x16x32_bf16(av.v, B2[1][3], i1, 0,0,0);

            float pa = (aci == 0) ? ps00 : ps10;
            float pb = (aci == 0) ? ps01 : ps11;
            #pragma unroll
            for (int q = 0; q < 4; ++q) {
                pa = fmaf(eA[q].x, r0[q], fmaf(-eA[q].y, i0[q], pa));
                pb = fmaf(eB[q].x, r1[q], fmaf(-eB[q].y, i1[q], pb));
            }
            if (aci == 0) { ps00 = pa; ps01 = pb; }
            else          { ps10 = pa; ps11 = pb; }
        }
    }

    // sum the 4 row-groups per column
    ps00 += __shfl_xor(ps00, 16, 64); ps00 += __shfl_xor(ps00, 32, 64);
    ps01 += __shfl_xor(ps01, 16, 64); ps01 += __shfl_xor(ps01, 32, 64);
    ps10 += __shfl_xor(ps10, 16, 64); ps10 += __shfl_xor(ps10, 32, 64);
    ps11 += __shfl_xor(ps11, 16, 64); ps11 += __shfl_xor(ps11, 32, 64);

    if (l < 32) {
        int s = l >> 4;
        int col = l & 15;
        float v0 = (s == 0) ? ps00 : ps01;
        float v1 = (s == 0) ? ps10 : ps11;
        int rk = rkbase + (s << 4) + col;
        Fre[(acb + 0) * 8192 + rk] = v0;
        Fre[(acb + 1) * 8192 + rk] = v1;
    }
}

// combine: out[t,c,k] = dcf[r,k]*scale * sum_a phi[a,t] * Fre[a*8+c][r*1024+k]
__global__ __launch_bounds__(256) void combine_kernel(
    const float* __restrict__ Fre, const float* __restrict__ phi,
    const float* __restrict__ dcf, const int* __restrict__ sidx,
    float* __restrict__ out)
{
    int idx = blockIdx.x * 256 + threadIdx.x;   // T*C*K/4 = 131072
    if (idx >= NT * NC * NK / 4) return;
    int k4 = idx & 255;
    int c  = (idx >> 8) & 7;
    int t  = idx >> 11;
    int r  = sidx[t];
    float4 d4 = *(const float4*)(dcf + (r << 10) + (k4 << 2));
    float4 acc = make_float4(0.f, 0.f, 0.f, 0.f);
    #pragma unroll
    for (int a = 0; a < 4; ++a) {
        float4 f = *(const float4*)(Fre + (((a << 3) + c) << 13) + (r << 10) + (k4 << 2));
        float ph = phi[a * 64 + t];
        acc.x = fmaf(ph, f.x, acc.x);
        acc.y = fmaf(ph, f.y, acc.y);
        acc.z = fmaf(ph, f.z, acc.z);
        acc.w = fmaf(ph, f.w, acc.w);
    }
    float s = 0.03125f;   // 2/sqrt(64*64)
    float4 o = make_float4(acc.x * d4.x * s, acc.y * d4.y * s,
                           acc.z * d4.z * s, acc.w * d4.w * s);
    *(float4*)(out + (idx << 2)) = o;
}

// ---------------- fallback (proven round-3 path, no ws needed) --------------
__global__ __launch_bounds__(256) void ndft_atomic_kernel(
    const float* __restrict__ xr, const float* __restrict__ xi,
    const float* __restrict__ mr, const float* __restrict__ mi,
    const float* __restrict__ trj,
    const float* __restrict__ phi, const float* __restrict__ dcf,
    const int* __restrict__ sidx, float* __restrict__ out)
{
    __shared__ float2 simg[64 * 64];
    int b = blockIdx.x;
    int kq = b & 3, c = (b >> 2) & 7, a = (b >> 5) & 3, r = b >> 7;
    int tid = threadIdx.x;
    for (int i = tid; i < 64 * 64; i += 256) {
        float xre = xr[(a << 12) + i], xim = xi[(a << 12) + i];
        float mre = mr[(c << 12) + i], mim = mi[(c << 12) + i];
        simg[i] = make_float2(xre * mre - xim * mim, xre * mim + xim * mre);
    }
    __syncthreads();
    int k = (kq << 8) + tid;
    float t0 = trj[(r << 11) + k];
    float t1 = trj[(r << 11) + 1024 + k];
    float sv, cv;
    sincosf(-t1, &sv, &cv);        float2 ewb = make_float2(cv, sv);
    sincosf(32.0f * t1, &sv, &cv); float2 ews = make_float2(cv, sv);
    sincosf(-t0, &sv, &cv);        float2 ehb = make_float2(cv, sv);
    sincosf(32.0f * t0, &sv, &cv); float2 ehc = make_float2(cv, sv);
    float accx = 0.f;
    for (int h0 = 0; h0 < 64; h0 += 4) {
        float2 s0 = make_float2(0.f, 0.f), s1 = s0, s2 = s0, s3 = s0;
        const float2* i0 = simg + (h0 << 6);
        float2 ewc = ews;
        #pragma unroll 8
        for (int w = 0; w < 64; ++w) {
            float2 v0 = i0[w], v1 = i0[w+64], v2 = i0[w+128], v3 = i0[w+192];
            s0.x = fmaf(v0.x, ewc.x, fmaf(-v0.y, ewc.y, s0.x));
            s0.y = fmaf(v0.x, ewc.y, fmaf( v0.y, ewc.x, s0.y));
            s1.x = fmaf(v1.x, ewc.x, fmaf(-v1.y, ewc.y, s1.x));
            s1.y = fmaf(v1.x, ewc.y, fmaf( v1.y, ewc.x, s1.y));
            s2.x = fmaf(v2.x, ewc.x, fmaf(-v2.y, ewc.y, s2.x));
            s2.y = fmaf(v2.x, ewc.y, fmaf( v2.y, ewc.x, s2.y));
            s3.x = fmaf(v3.x, ewc.x, fmaf(-v3.y, ewc.y, s3.x));
            s3.y = fmaf(v3.x, ewc.y, fmaf( v3.y, ewc.x, s3.y));
            ewc = cmul2(ewc, ewb);
        }
        float2 e0 = ehc, e1 = cmul2(e0, ehb), e2 = cmul2(e1, ehb), e3 = cmul2(e2, ehb);
        ehc = cmul2(e3, ehb);
        accx = fmaf(s0.x, e0.x, fmaf(-s0.y, e0.y, accx));
        accx = fmaf(s1.x, e1.x, fmaf(-s1.y, e1.y, accx));
        accx = fmaf(s2.x, e2.x, fmaf(-s2.y, e2.y, accx));
        accx = fmaf(s3.x, e3.x, fmaf(-s3.y, e3.y, accx));
    }
    float d = dcf[(r << 10) + k] * 0.03125f;
    for (int t = 0; t < 64; ++t) {
        if (sidx[t] == r) atomicAdd(out + (t << 13) + (c << 10) + k, phi[a*64 + t] * d * accx);
    }
}

extern "C" void kernel_launch(void* const* d_in, const int* in_sizes, int n_in,
                              void* d_out, int out_size, void* d_ws, size_t ws_size,
                              hipStream_t stream)
{
    const float* x_re   = (const float*)d_in[0];
    const float* x_im   = (const float*)d_in[1];
    const float* mps_re = (const float*)d_in[2];
    const float* mps_im = (const float*)d_in[3];
    const float* phi    = (const float*)d_in[4];
    const float* dcf    = (const float*)d_in[5];
    const float* trj    = (const float*)d_in[6];
    const int*   sidx   = (const int*)d_in[7];
    float* out = (float*)d_out;

    const size_t A_bytes = 512 * 1024;                 // packed A
    const size_t F_bytes = 32 * 8192 * sizeof(float);  // 1 MB Re(F)

    if (ws_size >= A_bytes + F_bytes) {
        uint4* Ap  = (uint4*)d_ws;
        float* Fre = (float*)((char*)d_ws + A_bytes);
        hipLaunchKernelGGL(prep_kernel, dim3(128), dim3(256), 0, stream,
                           x_re, x_im, mps_re, mps_im, Ap);
        hipLaunchKernelGGL(gemm2_kernel, dim3(1024), dim3(256), 0, stream,
                           Ap, trj, Fre);
        hipLaunchKernelGGL(combine_kernel, dim3(512), dim3(256), 0, stream,
                           Fre, phi, dcf, sidx, out);
    } else {
        hipMemsetAsync(d_out, 0, (size_t)out_size * sizeof(float), stream);
        hipLaunchKernelGGL(ndft_atomic_kernel, dim3(1024), dim3(256), 0, stream,
                           x_re, x_im, mps_re, mps_im, trj, phi, dcf, sidx, out);
    }
}

// Round 11
// 23.119 us; speedup vs baseline: 1.3421x; 1.0161x over previous
//
#include <hip/hip_runtime.h>
#include <hip/hip_bf16.h>
#include <math.h>

#define NT 64
#define NC 8
#define NK 1024

typedef __attribute__((ext_vector_type(8))) short bf16x8;
typedef __attribute__((ext_vector_type(4))) float f32x4;

__device__ __forceinline__ float2 cmul2(float2 a, float2 b) {
    return make_float2(fmaf(a.x, b.x, -a.y * b.y), fmaf(a.x, b.y, a.y * b.x));
}
// native trig; |x| <= ~101 rad -> err invisible under bf16 quantization
__device__ __forceinline__ void fast_sc(float x, float* s, float* c) {
    *s = __sinf(x); *c = __cosf(x);
}
__device__ __forceinline__ uint pack2(float x, float y) {
    __hip_bfloat162 h2 = __float22bfloat162_rn(make_float2(x, y));
    union { __hip_bfloat162 h; uint u; } cu; cu.h = h2; return cu.u;
}

// ---------------------------------------------------------------------------
// prep: pack A = [img_re, img_im] in MFMA-frag-linear order (R9-verified map):
// uint4 slot t = (ac*16 + mt*4 + chunk)*64 + l holds (re,im) pairs for
// h = mt*16 + (l&15), w = chunk*16 + (l>>4)*4 + i. 512 KB.
// ---------------------------------------------------------------------------
__global__ __launch_bounds__(256) void prep_kernel(
    const float* __restrict__ xr, const float* __restrict__ xi,
    const float* __restrict__ mr, const float* __restrict__ mi,
    uint4* __restrict__ Ap)
{
    int t = blockIdx.x * 256 + threadIdx.x;   // 32768
    int l = t & 63;
    int chunk = (t >> 6) & 3;
    int mt = (t >> 8) & 3;
    int ac = t >> 10;
    int a = ac >> 3, c = ac & 7;
    int h = (mt << 4) + (l & 15);
    int w0 = (chunk << 4) + ((l >> 4) << 2);
    int off = (h << 6) + w0;
    float4 x4r = *(const float4*)(xr + (a << 12) + off);
    float4 x4i = *(const float4*)(xi + (a << 12) + off);
    float4 m4r = *(const float4*)(mr + (c << 12) + off);
    float4 m4i = *(const float4*)(mi + (c << 12) + off);
    uint4 pk;
    pk.x = pack2(x4r.x * m4r.x - x4i.x * m4i.x, x4r.x * m4i.x + x4i.x * m4r.x);
    pk.y = pack2(x4r.y * m4r.y - x4i.y * m4i.y, x4r.y * m4i.y + x4i.y * m4r.y);
    pk.z = pack2(x4r.z * m4r.z - x4i.z * m4i.z, x4r.z * m4i.z + x4i.z * m4r.z);
    pk.w = pack2(x4r.w * m4r.w - x4i.w * m4i.w, x4r.w * m4i.w + x4i.w * m4r.w);
    Ap[t] = pk;
}

// ---------------------------------------------------------------------------
// fused gemm+combine: 1024 blocks = 256 rk-tiles x 4 c-pairs; 256 threads.
// Wave wv owns panels (a = wv, c = cpair*2 + {0,1}) -> block holds ALL a for
// its 2 c values, so the phi/dcf contraction fuses in-block. Inner loop is
// R9's verified gemm2. FIX vs R10: sphi staged by all 256 threads (256-thread
// block only covered sphi[0..191] before -> phi[a=3] was garbage).
// ---------------------------------------------------------------------------
__global__ __launch_bounds__(256) void fused_kernel(
    const uint4* __restrict__ Ap, const float* __restrict__ trj,
    const float* __restrict__ phi, const float* __restrict__ dcf,
    const int* __restrict__ sidx, float* __restrict__ out)
{
    __shared__ float Fs[8 * 33];     // [a*2+cc][kl]
    __shared__ float sphi[256];
    __shared__ int   ssidx[64];
    int b = blockIdx.x;              // 1024
    int rktile = b >> 2, cpair = b & 3;
    int tid = threadIdx.x;
    int wv = tid >> 6, l = tid & 63;
    int lg = l >> 4;
    int rkbase = rktile << 5;
    int r = rkbase >> 10;
    int acb = (wv << 3) + (cpair << 1);  // panel (a=wv, c=cpair*2), +1 = cc=1
    int wb = lg << 2;

    // stage sidx/phi early (overlaps main loop). 256 threads cover all 256 phi.
    sphi[tid] = phi[tid];
    if (tid < 64) ssidx[tid] = sidx[tid];

    int k0 = (rkbase + (l & 15)) & 1023;
    int k1 = (rkbase + 16 + (l & 15)) & 1023;
    float t0a = trj[(r << 11) + k0];
    float t0b = trj[(r << 11) + k1];
    float t1a = trj[(r << 11) + 1024 + k0];
    float t1b = trj[(r << 11) + 1024 + k1];

    // ---- B-frag generation (once per wave): B1=(Ewre,-Ewim), B2=(Ewim,Ewre)
    bf16x8 B1[2][4], B2[2][4];
    #pragma unroll
    for (int s = 0; s < 2; ++s) {
        float t1 = s ? t1b : t1a;
        float sv, cv;
        float2 e, st1, st16;
        fast_sc(t1 * (float)(32 - wb), &sv, &cv); e = make_float2(cv, sv);
        fast_sc(-t1, &sv, &cv);         st1  = make_float2(cv, sv);
        fast_sc(-16.0f * t1, &sv, &cv); st16 = make_float2(cv, sv);
        #pragma unroll
        for (int ch = 0; ch < 4; ++ch) {
            float2 ec = e;
            union { uint u[4]; bf16x8 v; } f1, f2;
            #pragma unroll
            for (int i = 0; i < 4; ++i) {
                f1.u[i] = pack2(ec.x, -ec.y);
                f2.u[i] = pack2(ec.y,  ec.x);
                ec = cmul2(ec, st1);
            }
            B1[s][ch] = f1.v; B2[s][ch] = f2.v;
            e = cmul2(e, st16);
        }
    }

    // ---- Eh bases/steps
    float sv, cv;
    float2 ehbA, ehbB, s1A, s1B, s16A, s16B;
    fast_sc(t0a * (float)(32 - wb), &sv, &cv); ehbA = make_float2(cv, sv);
    fast_sc(-t0a, &sv, &cv);         s1A  = make_float2(cv, sv);
    fast_sc(-16.0f * t0a, &sv, &cv); s16A = make_float2(cv, sv);
    fast_sc(t0b * (float)(32 - wb), &sv, &cv); ehbB = make_float2(cv, sv);
    fast_sc(-t0b, &sv, &cv);         s1B  = make_float2(cv, sv);
    fast_sc(-16.0f * t0b, &sv, &cv); s16B = make_float2(cv, sv);

    float ps00 = 0.f, ps01 = 0.f, ps10 = 0.f, ps11 = 0.f;  // [aci][sub]

    #pragma unroll
    for (int mt = 0; mt < 4; ++mt) {
        float2 eA[4], eB[4];
        eA[0] = ehbA; eB[0] = ehbB;
        #pragma unroll
        for (int q = 1; q < 4; ++q) {
            eA[q] = cmul2(eA[q-1], s1A);
            eB[q] = cmul2(eB[q-1], s1B);
        }
        ehbA = cmul2(ehbA, s16A);
        ehbB = cmul2(ehbB, s16B);

        #pragma unroll
        for (int aci = 0; aci < 2; ++aci) {
            int ac = acb + aci;
            const uint4* ap = Ap + (((ac << 4) + (mt << 2)) << 6) + l;
            uint4 a0 = ap[0];
            uint4 a1 = ap[64];
            uint4 a2 = ap[128];
            uint4 a3 = ap[192];
            f32x4 r0 = {0.f,0.f,0.f,0.f}, i0 = r0, r1 = r0, i1 = r0;
            union { uint4 u; bf16x8 v; } av;
            av.u = a0;
            r0 = __builtin_amdgcn_mfma_f32_16x16x32_bf16(av.v, B1[0][0], r0, 0,0,0);
            i0 = __builtin_amdgcn_mfma_f32_16x16x32_bf16(av.v, B2[0][0], i0, 0,0,0);
            r1 = __builtin_amdgcn_mfma_f32_16x16x32_bf16(av.v, B1[1][0], r1, 0,0,0);
            i1 = __builtin_amdgcn_mfma_f32_16x16x32_bf16(av.v, B2[1][0], i1, 0,0,0);
            av.u = a1;
            r0 = __builtin_amdgcn_mfma_f32_16x16x32_bf16(av.v, B1[0][1], r0, 0,0,0);
            i0 = __builtin_amdgcn_mfma_f32_16x16x32_bf16(av.v, B2[0][1], i0, 0,0,0);
            r1 = __builtin_amdgcn_mfma_f32_16x16x32_bf16(av.v, B1[1][1], r1, 0,0,0);
            i1 = __builtin_amdgcn_mfma_f32_16x16x32_bf16(av.v, B2[1][1], i1, 0,0,0);
            av.u = a2;
            r0 = __builtin_amdgcn_mfma_f32_16x16x32_bf16(av.v, B1[0][2], r0, 0,0,0);
            i0 = __builtin_amdgcn_mfma_f32_16x16x32_bf16(av.v, B2[0][2], i0, 0,0,0);
            r1 = __builtin_amdgcn_mfma_f32_16x16x32_bf16(av.v, B1[1][2], r1, 0,0,0);
            i1 = __builtin_amdgcn_mfma_f32_16x16x32_bf16(av.v, B2[1][2], i1, 0,0,0);
            av.u = a3;
            r0 = __builtin_amdgcn_mfma_f32_16x16x32_bf16(av.v, B1[0][3], r0, 0,0,0);
            i0 = __builtin_amdgcn_mfma_f32_16x16x32_bf16(av.v, B2[0][3], i0, 0,0,0);
            r1 = __builtin_amdgcn_mfma_f32_16x16x32_bf16(av.v, B1[1][3], r1, 0,0,0);
            i1 = __builtin_amdgcn_mfma_f32_16x16x32_bf16(av.v, B2[1][3], i1, 0,0,0);

            float pa = (aci == 0) ? ps00 : ps10;
            float pb = (aci == 0) ? ps01 : ps11;
            #pragma unroll
            for (int q = 0; q < 4; ++q) {
                pa = fmaf(eA[q].x, r0[q], fmaf(-eA[q].y, i0[q], pa));
                pb = fmaf(eB[q].x, r1[q], fmaf(-eB[q].y, i1[q], pb));
            }
            if (aci == 0) { ps00 = pa; ps01 = pb; }
            else          { ps10 = pa; ps11 = pb; }
        }
    }

    // sum the 4 row-groups per column
    ps00 += __shfl_xor(ps00, 16, 64); ps00 += __shfl_xor(ps00, 32, 64);
    ps01 += __shfl_xor(ps01, 16, 64); ps01 += __shfl_xor(ps01, 32, 64);
    ps10 += __shfl_xor(ps10, 16, 64); ps10 += __shfl_xor(ps10, 32, 64);
    ps11 += __shfl_xor(ps11, 16, 64); ps11 += __shfl_xor(ps11, 32, 64);

    if (l < 32) {
        int s = l >> 4;
        int kl = l & 31;
        float v0 = (s == 0) ? ps00 : ps01;   // panel aci=0 (cc=0)
        float v1 = (s == 0) ? ps10 : ps11;   // panel aci=1 (cc=1)
        Fs[(wv * 2 + 0) * 33 + kl] = v0;
        Fs[(wv * 2 + 1) * 33 + kl] = v1;
    }
    __syncthreads();

    // fused combine: out[t, cpair*2+cc, kgl] = dcf*scale * sum_a phi*Fs
    int kl = tid & 31, cc = (tid >> 5) & 1, tq = tid >> 6;
    int kgl = (rkbase & 1023) + kl;              // k within r
    int cglob = (cpair << 1) + cc;
    float dv = dcf[(r << 10) + kgl] * 0.03125f;  // scale = 2/sqrt(64*64)
    const float* Fsp = Fs + cc * 33 + kl;
    for (int t = tq; t < NT; t += 4) {
        if (ssidx[t] != r) continue;
        float s = 0.f;
        #pragma unroll
        for (int a = 0; a < 4; ++a)
            s = fmaf(sphi[a * 64 + t], Fsp[a * 66], s);   // 66 = 2*33
        out[(t << 13) + (cglob << 10) + kgl] = s * dv;
    }
}

// ---------------- fallback (proven round-3 path, no ws needed) --------------
__global__ __launch_bounds__(256) void ndft_atomic_kernel(
    const float* __restrict__ xr, const float* __restrict__ xi,
    const float* __restrict__ mr, const float* __restrict__ mi,
    const float* __restrict__ trj,
    const float* __restrict__ phi, const float* __restrict__ dcf,
    const int* __restrict__ sidx, float* __restrict__ out)
{
    __shared__ float2 simg[64 * 64];
    int b = blockIdx.x;
    int kq = b & 3, c = (b >> 2) & 7, a = (b >> 5) & 3, r = b >> 7;
    int tid = threadIdx.x;
    for (int i = tid; i < 64 * 64; i += 256) {
        float xre = xr[(a << 12) + i], xim = xi[(a << 12) + i];
        float mre = mr[(c << 12) + i], mim = mi[(c << 12) + i];
        simg[i] = make_float2(xre * mre - xim * mim, xre * mim + xim * mre);
    }
    __syncthreads();
    int k = (kq << 8) + tid;
    float t0 = trj[(r << 11) + k];
    float t1 = trj[(r << 11) + 1024 + k];
    float sv, cv;
    sincosf(-t1, &sv, &cv);        float2 ewb = make_float2(cv, sv);
    sincosf(32.0f * t1, &sv, &cv); float2 ews = make_float2(cv, sv);
    sincosf(-t0, &sv, &cv);        float2 ehb = make_float2(cv, sv);
    sincosf(32.0f * t0, &sv, &cv); float2 ehc = make_float2(cv, sv);
    float accx = 0.f;
    for (int h0 = 0; h0 < 64; h0 += 4) {
        float2 s0 = make_float2(0.f, 0.f), s1 = s0, s2 = s0, s3 = s0;
        const float2* i0 = simg + (h0 << 6);
        float2 ewc = ews;
        #pragma unroll 8
        for (int w = 0; w < 64; ++w) {
            float2 v0 = i0[w], v1 = i0[w+64], v2 = i0[w+128], v3 = i0[w+192];
            s0.x = fmaf(v0.x, ewc.x, fmaf(-v0.y, ewc.y, s0.x));
            s0.y = fmaf(v0.x, ewc.y, fmaf( v0.y, ewc.x, s0.y));
            s1.x = fmaf(v1.x, ewc.x, fmaf(-v1.y, ewc.y, s1.x));
            s1.y = fmaf(v1.x, ewc.y, fmaf( v1.y, ewc.x, s1.y));
            s2.x = fmaf(v2.x, ewc.x, fmaf(-v2.y, ewc.y, s2.x));
            s2.y = fmaf(v2.x, ewc.y, fmaf( v2.y, ewc.x, s2.y));
            s3.x = fmaf(v3.x, ewc.x, fmaf(-v3.y, ewc.y, s3.x));
            s3.y = fmaf(v3.x, ewc.y, fmaf( v3.y, ewc.x, s3.y));
            ewc = cmul2(ewc, ewb);
        }
        float2 e0 = ehc, e1 = cmul2(e0, ehb), e2 = cmul2(e1, ehb), e3 = cmul2(e2, ehb);
        ehc = cmul2(e3, ehb);
        accx = fmaf(s0.x, e0.x, fmaf(-s0.y, e0.y, accx));
        accx = fmaf(s1.x, e1.x, fmaf(-s1.y, e1.y, accx));
        accx = fmaf(s2.x, e2.x, fmaf(-s2.y, e2.y, accx));
        accx = fmaf(s3.x, e3.x, fmaf(-s3.y, e3.y, accx));
    }
    float d = dcf[(r << 10) + k] * 0.03125f;
    for (int t = 0; t < 64; ++t) {
        if (sidx[t] == r) atomicAdd(out + (t << 13) + (c << 10) + k, phi[a*64 + t] * d * accx);
    }
}

extern "C" void kernel_launch(void* const* d_in, const int* in_sizes, int n_in,
                              void* d_out, int out_size, void* d_ws, size_t ws_size,
                              hipStream_t stream)
{
    const float* x_re   = (const float*)d_in[0];
    const float* x_im   = (const float*)d_in[1];
    const float* mps_re = (const float*)d_in[2];
    const float* mps_im = (const float*)d_in[3];
    const float* phi    = (const float*)d_in[4];
    const float* dcf    = (const float*)d_in[5];
    const float* trj    = (const float*)d_in[6];
    const int*   sidx   = (const int*)d_in[7];
    float* out = (float*)d_out;

    const size_t A_bytes = 512 * 1024;   // packed A

    if (ws_size >= A_bytes) {
        uint4* Ap = (uint4*)d_ws;
        hipLaunchKernelGGL(prep_kernel, dim3(128), dim3(256), 0, stream,
                           x_re, x_im, mps_re, mps_im, Ap);
        hipLaunchKernelGGL(fused_kernel, dim3(1024), dim3(256), 0, stream,
                           Ap, trj, phi, dcf, sidx, out);
    } else {
        hipMemsetAsync(d_out, 0, (size_t)out_size * sizeof(float), stream);
        hipLaunchKernelGGL(ndft_atomic_kernel, dim3(1024), dim3(256), 0, stream,
                           x_re, x_im, mps_re, mps_im, trj, phi, dcf, sidx, out);
    }
}